// Round 2
// baseline (535.392 us; speedup 1.0000x reference)
//
#include <hip/hip_runtime.h>
#include <stdint.h>
#include <stddef.h>

typedef unsigned short u16;
typedef __attribute__((ext_vector_type(8))) short short8;
typedef __attribute__((ext_vector_type(4))) float f32x4;
typedef __attribute__((ext_vector_type(4))) unsigned short ushort4v;
typedef __attribute__((ext_vector_type(4))) unsigned char uchar4v;
typedef __attribute__((ext_vector_type(2))) unsigned int uint2v;

constexpr int B_ = 8, S_ = 1024, HID_ = 1024, NH_ = 16, HD_ = 64;

__device__ __forceinline__ u16 f2b(float f) {
  unsigned int u = __builtin_bit_cast(unsigned int, f);
  u += 0x7fff + ((u >> 16) & 1);   // RNE
  return (u16)(u >> 16);
}
__device__ __forceinline__ float b2f(u16 s) {
  unsigned int u = ((unsigned int)s) << 16;
  return __builtin_bit_cast(float, u);
}
__device__ __forceinline__ void llds16(const void* g, void* l) {
  __builtin_amdgcn_global_load_lds((__attribute__((address_space(1))) void*)g,
                                   (__attribute__((address_space(3))) void*)l, 16, 0, 0);
}

// ---------------- fp32 -> bf16 conversions ----------------
__global__ __launch_bounds__(256) void prep_cvt(
    const float* __restrict__ x, const float* __restrict__ wqkv,
    const float* __restrict__ wout, u16* __restrict__ xb,
    u16* __restrict__ wqkvb, u16* __restrict__ woutb) {
  const int NX4 = B_ * S_ * HID_ / 4, NW14 = 3 * HID_ * HID_ / 4, NW24 = HID_ * HID_ / 4;
  const int tot = NX4 + NW14 + NW24;
  for (int i = blockIdx.x * blockDim.x + threadIdx.x; i < tot; i += gridDim.x * blockDim.x) {
    const float4* s; u16* d; int j;
    if (i < NX4)              { s = (const float4*)x;    d = xb;    j = i; }
    else if (i < NX4 + NW14)  { s = (const float4*)wqkv; d = wqkvb; j = i - NX4; }
    else                      { s = (const float4*)wout; d = woutb; j = i - NX4 - NW14; }
    float4 v = s[j];
    ushort4v o; o[0] = f2b(v.x); o[1] = f2b(v.y); o[2] = f2b(v.z); o[3] = f2b(v.w);
    *(ushort4v*)(d + 4 * (size_t)j) = o;
  }
}

// ---------------- rel_pos + rel_2d_pos -> bf16, permuted to S^T C-fragment order ----
// layout: elem (h, q, k): ktg=k>>4, qtg=q>>4, qk=(k&15)>>2, rk=k&3, lq=q&15
// flat = (((h*64+ktg)*64+qtg)*4+qk)*64 + lq*4 + rk
__global__ __launch_bounds__(256) void rel_perm(
    const float* __restrict__ a, const float* __restrict__ b, u16* __restrict__ relb) {
  __shared__ u16 lbuf[16384];
  const int ktg = blockIdx.x, h = blockIdx.y;
  const int t = threadIdx.x;
#pragma unroll
  for (int it = 0; it < 16; ++it) {
    int idx = it * 256 + t;            // 0..4095
    int q = idx >> 2, k4 = (idx & 3) * 4;
    size_t src = ((size_t)h * S_ + q) * S_ + ktg * 16 + k4;
    float4 va = *(const float4*)(a + src);
    float4 vb = *(const float4*)(b + src);
    int qk = k4 >> 2, lq = q & 15, qtg = q >> 4;
    unsigned int d0 = (unsigned)f2b(va.x + vb.x) | ((unsigned)f2b(va.y + vb.y) << 16);
    unsigned int d1 = (unsigned)f2b(va.z + vb.z) | ((unsigned)f2b(va.w + vb.w) << 16);
    uint2v pw; pw[0] = d0; pw[1] = d1;
    *(uint2v*)(lbuf + (qtg * 4 + qk) * 64 + (lq ^ (qk * 4)) * 4) = pw;  // xor-swizzle: conflict-free
  }
  __syncthreads();
  const size_t obase = ((size_t)(h * 64 + ktg)) << 14;
#pragma unroll
  for (int it = 0; it < 8; ++it) {
    int e = (it * 256 + t) * 8;       // output element index, short8 granules
    int qtqk = e >> 6, lq = (e >> 2) & 15, qk = qtqk & 3;
    short8 v = *(const short8*)(lbuf + qtqk * 64 + (lq ^ (qk * 4)) * 4);
    *(short8*)(relb + obase + e) = v;
  }
}

// ---------------- QKV projection GEMM, D[o][s] orientation ----------------
__global__ __launch_bounds__(256) void gemm_qkv(
    const u16* __restrict__ W, const u16* __restrict__ X,
    const float* __restrict__ qbias, const float* __restrict__ vbias,
    u16* __restrict__ Qb, u16* __restrict__ Kb, u16* __restrict__ Vtb) {
  constexpr int K = HID_;
  __shared__ u16 Ws[128 * 32];
  __shared__ u16 Xs[128 * 32];
  const int o0 = blockIdx.x * 128, s0 = blockIdx.y * 128;
  const int t = threadIdx.x, lane = t & 63, wv = t >> 6;
  const int wr = wv >> 1, wc = wv & 1, ln = lane & 15, q8 = lane >> 4;
  f32x4 acc[4][4] = {};

  for (int kt = 0; kt < K / 32; ++kt) {
    const int k0 = kt * 32;
#pragma unroll
    for (int c = 0; c < 2; ++c) {
      int idx = c * 256 + t, row = idx >> 2, cc = (idx & 3) * 8;
      llds16(W + (size_t)(o0 + row) * K + k0 + cc, Ws + (size_t)(c * 256 + wv * 64) * 8);
      llds16(X + (size_t)(s0 + row) * K + k0 + cc, Xs + (size_t)(c * 256 + wv * 64) * 8);
    }
    __syncthreads();
    short8 of[4], sf[4];
#pragma unroll
    for (int mi = 0; mi < 4; ++mi)
      of[mi] = *(const short8*)(Ws + (wr * 64 + mi * 16 + ln) * 32 + q8 * 8);
#pragma unroll
    for (int ni = 0; ni < 4; ++ni)
      sf[ni] = *(const short8*)(Xs + (wc * 64 + ni * 16 + ln) * 32 + q8 * 8);
#pragma unroll
    for (int mi = 0; mi < 4; ++mi)
#pragma unroll
      for (int ni = 0; ni < 4; ++ni)
        acc[mi][ni] = __builtin_amdgcn_mfma_f32_16x16x32_bf16(of[mi], sf[ni], acc[mi][ni], 0, 0, 0);
    __syncthreads();
  }

  const int sec = o0 >> 10;   // 0=Q 1=K 2=V (block-uniform)
#pragma unroll
  for (int mi = 0; mi < 4; ++mi) {
    const int ob = o0 + wr * 64 + mi * 16 + q8 * 4;
    const int oo = ob & 1023, hh = oo >> 6, dd = oo & 63;
#pragma unroll
    for (int ni = 0; ni < 4; ++ni) {
      const int s = s0 + wc * 64 + ni * 16 + ln;
      const int bb = s >> 10, ss = s & 1023;
      if (sec == 0) {
        float4 bias = *(const float4*)(qbias + oo);
        ushort4v st;
#pragma unroll
        for (int r = 0; r < 4; ++r) st[r] = f2b((acc[mi][ni][r] + ((const float*)&bias)[r]) * 0.125f);
        *(ushort4v*)(Qb + ((size_t)(bb * NH_ + hh) * S_ + ss) * HD_ + dd) = st;
      } else if (sec == 1) {
        ushort4v st;
#pragma unroll
        for (int r = 0; r < 4; ++r) st[r] = f2b(acc[mi][ni][r]);
        *(ushort4v*)(Kb + ((size_t)(bb * NH_ + hh) * S_ + ss) * HD_ + dd) = st;
      } else {
        float4 bias = *(const float4*)(vbias + oo);
#pragma unroll
        for (int r = 0; r < 4; ++r)
          Vtb[((size_t)(bb * NH_ + hh) * HD_ + dd + r) * S_ + ss] =
              f2b(acc[mi][ni][r] + ((const float*)&bias)[r]);
      }
    }
  }
}

// ---------------- flash attention: S^T = K·Q^T, fixed-shift softmax, O^T = V^T·P^T ----
__global__ __launch_bounds__(256, 3) void flash_attn(
    const u16* __restrict__ Qb, const u16* __restrict__ Kb,
    const u16* __restrict__ Vtb, const u16* __restrict__ relb,
    const unsigned char* __restrict__ mask, u16* __restrict__ ctxb) {
  const int qt_blk = blockIdx.x, h = blockIdx.y, b = blockIdx.z;
  const int bh = b * NH_ + h, q0 = qt_blk * 128;
  const int t = threadIdx.x, lane = t & 63, wv = t >> 6;
  const int ln = lane & 15, q8 = lane >> 4;

  __shared__ u16 Ks[128 * 72];      // [k][64+8]
  __shared__ u16 Vts[64 * 136];     // [d][128+8]
  __shared__ u16 Pbuf[4 * 32 * 40]; // per-wave [q 32][32+8]  (80B pitch: 16B-aligned rows)
  u16* Pw = Pbuf + wv * 1280;

  short8 qf[2][2];   // [qt][kc] : Q[q=ln][d=kc*32+q8*8..]
#pragma unroll
  for (int qt = 0; qt < 2; ++qt)
#pragma unroll
    for (int kc = 0; kc < 2; ++kc)
      qf[qt][kc] = *(const short8*)(Qb + ((size_t)bh * S_ + q0 + wv * 32 + qt * 16 + ln) * HD_ + kc * 32 + q8 * 8);

  f32x4 Oa[4][2] = {};   // [mt(d)][qt]
  float rs[2] = {0.f, 0.f};

  for (int kt128 = 0; kt128 < 8; ++kt128) {
    const int k0 = kt128 * 128;
    __syncthreads();
#pragma unroll
    for (int i = 0; i < 4; ++i) {   // stage K tile [128][64]
      int idx = i * 256 + t, row = idx >> 3, c8 = (idx & 7) * 8;
      *(short8*)(Ks + row * 72 + c8) =
          *(const short8*)(Kb + ((size_t)bh * S_ + k0 + row) * HD_ + c8);
    }
#pragma unroll
    for (int i = 0; i < 4; ++i) {   // stage V^T tile [64][128]
      int idx = i * 256 + t, row = idx >> 4, c8 = (idx & 15) * 8;
      *(short8*)(Vts + row * 136 + c8) =
          *(const short8*)(Vtb + ((size_t)bh * HD_ + row) * S_ + k0 + c8);
    }
    __syncthreads();

#pragma unroll
    for (int kvc = 0; kvc < 4; ++kvc) {
#pragma unroll
      for (int sub = 0; sub < 2; ++sub) {
        const int kt = kvc * 2 + sub;
        short8 kf0 = *(const short8*)(Ks + (kt * 16 + ln) * 72 + q8 * 8);
        short8 kf1 = *(const short8*)(Ks + (kt * 16 + ln) * 72 + 32 + q8 * 8);
        uchar4v m4 = *(const uchar4v*)(mask + b * S_ + k0 + kt * 16 + q8 * 4);
        f32x4 mbase;
#pragma unroll
        for (int r = 0; r < 4; ++r) mbase[r] = (m4[r] ? -1e30f : 0.f) - 8.0f;  // fixed shift
        const int ktg = kt128 * 8 + kt;
#pragma unroll
        for (int qt = 0; qt < 2; ++qt) {
          const int qtg = qt_blk * 8 + wv * 2 + qt;
          ushort4v r4 = *(const ushort4v*)(relb +
              ((((size_t)h * 64 + ktg) * 64 + qtg) * 4 + q8) * 64 + ln * 4);
          f32x4 sc;
#pragma unroll
          for (int r = 0; r < 4; ++r) sc[r] = b2f(r4[r]) + mbase[r];
          sc = __builtin_amdgcn_mfma_f32_16x16x32_bf16(kf0, qf[qt][0], sc, 0, 0, 0);
          sc = __builtin_amdgcn_mfma_f32_16x16x32_bf16(kf1, qf[qt][1], sc, 0, 0, 0);
          float p0 = __expf(sc[0]), p1 = __expf(sc[1]);
          float p2 = __expf(sc[2]), p3 = __expf(sc[3]);
          rs[qt] += (p0 + p1) + (p2 + p3);
          uint2v pw;
          pw[0] = (unsigned)f2b(p0) | ((unsigned)f2b(p1) << 16);
          pw[1] = (unsigned)f2b(p2) | ((unsigned)f2b(p3) << 16);
          *(uint2v*)(Pw + (qt * 16 + ln) * 40 + sub * 16 + q8 * 4) = pw;  // P[q][k] b64
        }
      }
      // PV: O^T[d][q] += V^T-rows · P-rows  (kdim = 32 keys of this chunk)
      short8 pf0 = *(const short8*)(Pw + ln * 40 + q8 * 8);
      short8 pf1 = *(const short8*)(Pw + (16 + ln) * 40 + q8 * 8);
#pragma unroll
      for (int mt = 0; mt < 4; ++mt) {
        short8 vf = *(const short8*)(Vts + (mt * 16 + ln) * 136 + kvc * 32 + q8 * 8);
        Oa[mt][0] = __builtin_amdgcn_mfma_f32_16x16x32_bf16(vf, pf0, Oa[mt][0], 0, 0, 0);
        Oa[mt][1] = __builtin_amdgcn_mfma_f32_16x16x32_bf16(vf, pf1, Oa[mt][1], 0, 0, 0);
      }
    }
  }

  float inv[2];
#pragma unroll
  for (int qt = 0; qt < 2; ++qt) {
    rs[qt] += __shfl_xor(rs[qt], 16, 64);
    rs[qt] += __shfl_xor(rs[qt], 32, 64);
    inv[qt] = 1.f / rs[qt];
  }
#pragma unroll
  for (int mt = 0; mt < 4; ++mt)
#pragma unroll
    for (int qt = 0; qt < 2; ++qt) {
      const int q = q0 + wv * 32 + qt * 16 + ln;
      ushort4v st;
#pragma unroll
      for (int r = 0; r < 4; ++r) st[r] = f2b(Oa[mt][qt][r] * inv[qt]);
      *(ushort4v*)(ctxb + ((size_t)(b * S_ + q)) * HID_ + h * 64 + mt * 16 + q8 * 4) = st;
    }
}

// ---------------- output projection GEMM, D[o][s]; +bias +residual ----------------
__global__ __launch_bounds__(256) void gemm_out(
    const u16* __restrict__ W, const u16* __restrict__ X,
    const float* __restrict__ bout, const float* __restrict__ xres,
    u16* __restrict__ hb) {
  constexpr int K = HID_;
  __shared__ u16 Ws[128 * 32];
  __shared__ u16 Xs[128 * 32];
  const int o0 = blockIdx.x * 128, s0 = blockIdx.y * 128;
  const int t = threadIdx.x, lane = t & 63, wv = t >> 6;
  const int wr = wv >> 1, wc = wv & 1, ln = lane & 15, q8 = lane >> 4;
  f32x4 acc[4][4] = {};

  for (int kt = 0; kt < K / 32; ++kt) {
    const int k0 = kt * 32;
#pragma unroll
    for (int c = 0; c < 2; ++c) {
      int idx = c * 256 + t, row = idx >> 2, cc = (idx & 3) * 8;
      llds16(W + (size_t)(o0 + row) * K + k0 + cc, Ws + (size_t)(c * 256 + wv * 64) * 8);
      llds16(X + (size_t)(s0 + row) * K + k0 + cc, Xs + (size_t)(c * 256 + wv * 64) * 8);
    }
    __syncthreads();
    short8 of[4], sf[4];
#pragma unroll
    for (int mi = 0; mi < 4; ++mi)
      of[mi] = *(const short8*)(Ws + (wr * 64 + mi * 16 + ln) * 32 + q8 * 8);
#pragma unroll
    for (int ni = 0; ni < 4; ++ni)
      sf[ni] = *(const short8*)(Xs + (wc * 64 + ni * 16 + ln) * 32 + q8 * 8);
#pragma unroll
    for (int mi = 0; mi < 4; ++mi)
#pragma unroll
      for (int ni = 0; ni < 4; ++ni)
        acc[mi][ni] = __builtin_amdgcn_mfma_f32_16x16x32_bf16(of[mi], sf[ni], acc[mi][ni], 0, 0, 0);
    __syncthreads();
  }

#pragma unroll
  for (int mi = 0; mi < 4; ++mi) {
    const int ob = o0 + wr * 64 + mi * 16 + q8 * 4;
    float4 b4 = *(const float4*)(bout + ob);
#pragma unroll
    for (int ni = 0; ni < 4; ++ni) {
      const int s = s0 + wc * 64 + ni * 16 + ln;
      float4 x4 = *(const float4*)(xres + (size_t)s * HID_ + ob);
      ushort4v st;
#pragma unroll
      for (int r = 0; r < 4; ++r)
        st[r] = f2b(acc[mi][ni][r] + ((const float*)&b4)[r] + ((const float*)&x4)[r]);
      *(ushort4v*)(hb + (size_t)s * HID_ + ob) = st;
    }
  }
}

// ---------------- LayerNorm, one wave per row ----------------
__global__ __launch_bounds__(256) void ln_kernel(
    const u16* __restrict__ hb, const float* __restrict__ gamma,
    const float* __restrict__ beta, float* __restrict__ out) {
  const int lane = threadIdx.x & 63, wv = threadIdx.x >> 6;
  const int row = blockIdx.x * 4 + wv;
  const u16* hr = hb + (size_t)row * HID_;
  float v[16];
  short8 a = *(const short8*)(hr + lane * 16);
  short8 c = *(const short8*)(hr + lane * 16 + 8);
#pragma unroll
  for (int j = 0; j < 8; ++j) { v[j] = b2f((u16)a[j]); v[8 + j] = b2f((u16)c[j]); }
  float sum = 0.f, sq = 0.f;
#pragma unroll
  for (int j = 0; j < 16; ++j) { sum += v[j]; sq += v[j] * v[j]; }
#pragma unroll
  for (int off = 1; off < 64; off <<= 1) {
    sum += __shfl_xor(sum, off, 64);
    sq  += __shfl_xor(sq, off, 64);
  }
  const float mu = sum * (1.f / HID_);
  const float var = sq * (1.f / HID_) - mu * mu;
  const float inv = 1.f / sqrtf(var + 1e-12f);
#pragma unroll
  for (int j = 0; j < 16; ++j) {
    const int n = lane * 16 + j;
    out[(size_t)row * HID_ + n] = (v[j] - mu) * inv * gamma[n] + beta[n];
  }
}

extern "C" void kernel_launch(void* const* d_in, const int* in_sizes, int n_in,
                              void* d_out, int out_size, void* d_ws, size_t ws_size,
                              hipStream_t stream) {
  (void)in_sizes; (void)n_in; (void)out_size; (void)ws_size;
  const float* x     = (const float*)d_in[0];
  const unsigned char* mask = (const unsigned char*)d_in[1];
  const float* relp  = (const float*)d_in[2];
  const float* rel2  = (const float*)d_in[3];
  const float* wqkv  = (const float*)d_in[4];
  const float* qbias = (const float*)d_in[5];
  const float* vbias = (const float*)d_in[6];
  const float* wout  = (const float*)d_in[7];
  const float* bout  = (const float*)d_in[8];
  const float* gamma = (const float*)d_in[9];
  const float* beta  = (const float*)d_in[10];
  float* out = (float*)d_out;

  char* ws = (char*)d_ws;
  const size_t MB = (size_t)1 << 20;
  u16* xb    = (u16*)(ws + 0 * MB);    // 16 MB
  u16* wqkvb = (u16*)(ws + 16 * MB);   // 6 MB
  u16* woutb = (u16*)(ws + 22 * MB);   // 2 MB
  u16* relb  = (u16*)(ws + 24 * MB);   // 32 MB (permuted)
  u16* Qb    = (u16*)(ws + 56 * MB);   // 16 MB
  u16* Kb    = (u16*)(ws + 72 * MB);   // 16 MB
  u16* Vtb   = (u16*)(ws + 88 * MB);   // 16 MB  [B,NH,HD,S]
  u16* ctxb  = (u16*)(ws + 104 * MB);  // 16 MB
  u16* hb    = (u16*)(ws + 120 * MB);  // 16 MB

  prep_cvt<<<1024, 256, 0, stream>>>(x, wqkv, wout, xb, wqkvb, woutb);
  rel_perm<<<dim3(64, 16), 256, 0, stream>>>(relp, rel2, relb);
  gemm_qkv<<<dim3(24, 64), 256, 0, stream>>>(wqkvb, xb, qbias, vbias, Qb, Kb, Vtb);
  flash_attn<<<dim3(8, 16, 8), 256, 0, stream>>>(Qb, Kb, Vtb, relb, mask, ctxb);
  gemm_out<<<dim3(8, 64), 256, 0, stream>>>(woutb, ctxb, bout, x, hb);
  ln_kernel<<<2048, 256, 0, stream>>>(hb, gamma, beta, out);
}

// Round 3
// 473.476 us; speedup vs baseline: 1.1308x; 1.1308x over previous
//
#include <hip/hip_runtime.h>
#include <stdint.h>
#include <stddef.h>

typedef unsigned short u16;
typedef __attribute__((ext_vector_type(8))) short short8;
typedef __attribute__((ext_vector_type(4))) float f32x4;
typedef __attribute__((ext_vector_type(4))) unsigned short ushort4v;
typedef __attribute__((ext_vector_type(4))) unsigned char uchar4v;
typedef __attribute__((ext_vector_type(2))) unsigned int uint2v;

constexpr int B_ = 8, S_ = 1024, HID_ = 1024, NH_ = 16, HD_ = 64;

__device__ __forceinline__ u16 f2b(float f) {
  unsigned int u = __builtin_bit_cast(unsigned int, f);
  u += 0x7fff + ((u >> 16) & 1);   // RNE
  return (u16)(u >> 16);
}
__device__ __forceinline__ float b2f(u16 s) {
  unsigned int u = ((unsigned int)s) << 16;
  return __builtin_bit_cast(float, u);
}
__device__ __forceinline__ void llds16(const void* g, void* l) {
  __builtin_amdgcn_global_load_lds((__attribute__((address_space(1))) void*)g,
                                   (__attribute__((address_space(3))) void*)l, 16, 0, 0);
}

// ---------------- fp32 -> bf16 conversions ----------------
__global__ __launch_bounds__(256) void prep_cvt(
    const float* __restrict__ x, const float* __restrict__ wqkv,
    const float* __restrict__ wout, u16* __restrict__ xb,
    u16* __restrict__ wqkvb, u16* __restrict__ woutb) {
  const int NX4 = B_ * S_ * HID_ / 4, NW14 = 3 * HID_ * HID_ / 4, NW24 = HID_ * HID_ / 4;
  const int tot = NX4 + NW14 + NW24;
  for (int i = blockIdx.x * blockDim.x + threadIdx.x; i < tot; i += gridDim.x * blockDim.x) {
    const float4* s; u16* d; int j;
    if (i < NX4)              { s = (const float4*)x;    d = xb;    j = i; }
    else if (i < NX4 + NW14)  { s = (const float4*)wqkv; d = wqkvb; j = i - NX4; }
    else                      { s = (const float4*)wout; d = woutb; j = i - NX4 - NW14; }
    float4 v = s[j];
    ushort4v o; o[0] = f2b(v.x); o[1] = f2b(v.y); o[2] = f2b(v.z); o[3] = f2b(v.w);
    *(ushort4v*)(d + 4 * (size_t)j) = o;
  }
}

// ---------------- rel_pos + rel_2d_pos -> bf16, permuted to S^T C-fragment order ----
// elem (h,q,k): ktg=k>>4, qtg=q>>4, qk=(k&15)>>2, rk=k&3, lq=q&15
// flat = (((h*64+ktg)*64+qtg)*4+qk)*64 + lq*4 + rk
// block = (qtg,h): reads 16 fully-contiguous 4KB q-rows of a and b.
__global__ __launch_bounds__(256) void rel_perm(
    const float* __restrict__ a, const float* __restrict__ b, u16* __restrict__ relb) {
  __shared__ u16 lbuf[16 * 1032];   // [lq][k], pitch 1032 to break bank stride
  const int qtg = blockIdx.x, h = blockIdx.y;
  const int t = threadIdx.x;
#pragma unroll
  for (int it = 0; it < 16; ++it) {
    int idx = it * 256 + t;                 // 0..4095
    int lq = idx >> 8, kc = idx & 255;      // kc: float4 index within row
    size_t src = ((size_t)h * S_ + qtg * 16 + lq) * S_ + kc * 4;
    float4 va = *(const float4*)(a + src);
    float4 vb = *(const float4*)(b + src);
    ushort4v o;
    o[0] = f2b(va.x + vb.x); o[1] = f2b(va.y + vb.y);
    o[2] = f2b(va.z + vb.z); o[3] = f2b(va.w + vb.w);
    *(ushort4v*)(lbuf + lq * 1032 + kc * 4) = o;
  }
  __syncthreads();
#pragma unroll
  for (int it = 0; it < 16; ++it) {
    int c = it * 16 + (t >> 4);             // chunk 0..255 = ktg*4+qk
    int ktg = c >> 2, qk = c & 3, lq = t & 15;
    ushort4v v = *(const ushort4v*)(lbuf + lq * 1032 + ktg * 16 + qk * 4);
    *(ushort4v*)(relb + ((((size_t)h * 64 + ktg) * 64 + qtg) * 4 + qk) * 64 + lq * 4) = v;
  }
}

// ---------------- QKV projection GEMM, D[o][s] orientation ----------------
__global__ __launch_bounds__(256) void gemm_qkv(
    const u16* __restrict__ W, const u16* __restrict__ X,
    const float* __restrict__ qbias, const float* __restrict__ vbias,
    u16* __restrict__ Qb, u16* __restrict__ Kb, u16* __restrict__ Vb) {
  constexpr int K = HID_;
  __shared__ u16 Ws[128 * 32];
  __shared__ u16 Xs[128 * 32];
  const int o0 = blockIdx.x * 128, s0 = blockIdx.y * 128;
  const int t = threadIdx.x, lane = t & 63, wv = t >> 6;
  const int wr = wv >> 1, wc = wv & 1, ln = lane & 15, q8 = lane >> 4;
  f32x4 acc[4][4] = {};

  for (int kt = 0; kt < K / 32; ++kt) {
    const int k0 = kt * 32;
#pragma unroll
    for (int c = 0; c < 2; ++c) {
      int idx = c * 256 + t, row = idx >> 2, cc = (idx & 3) * 8;
      llds16(W + (size_t)(o0 + row) * K + k0 + cc, Ws + (size_t)(c * 256 + wv * 64) * 8);
      llds16(X + (size_t)(s0 + row) * K + k0 + cc, Xs + (size_t)(c * 256 + wv * 64) * 8);
    }
    __syncthreads();
    short8 of[4], sf[4];
#pragma unroll
    for (int mi = 0; mi < 4; ++mi)
      of[mi] = *(const short8*)(Ws + (wr * 64 + mi * 16 + ln) * 32 + q8 * 8);
#pragma unroll
    for (int ni = 0; ni < 4; ++ni)
      sf[ni] = *(const short8*)(Xs + (wc * 64 + ni * 16 + ln) * 32 + q8 * 8);
#pragma unroll
    for (int mi = 0; mi < 4; ++mi)
#pragma unroll
      for (int ni = 0; ni < 4; ++ni)
        acc[mi][ni] = __builtin_amdgcn_mfma_f32_16x16x32_bf16(of[mi], sf[ni], acc[mi][ni], 0, 0, 0);
    __syncthreads();
  }

  const int sec = o0 >> 10;   // 0=Q 1=K 2=V (block-uniform)
#pragma unroll
  for (int mi = 0; mi < 4; ++mi) {
    const int ob = o0 + wr * 64 + mi * 16 + q8 * 4;
    const int oo = ob & 1023, hh = oo >> 6, dd = oo & 63;
#pragma unroll
    for (int ni = 0; ni < 4; ++ni) {
      const int s = s0 + wc * 64 + ni * 16 + ln;
      const int bb = s >> 10, ss = s & 1023;
      size_t dst = ((size_t)(bb * NH_ + hh) * S_ + ss) * HD_ + dd;
      if (sec == 0) {
        float4 bias = *(const float4*)(qbias + oo);
        ushort4v st;
#pragma unroll
        for (int r = 0; r < 4; ++r) st[r] = f2b((acc[mi][ni][r] + ((const float*)&bias)[r]) * 0.125f);
        *(ushort4v*)(Qb + dst) = st;
      } else if (sec == 1) {
        ushort4v st;
#pragma unroll
        for (int r = 0; r < 4; ++r) st[r] = f2b(acc[mi][ni][r]);
        *(ushort4v*)(Kb + dst) = st;
      } else {
        float4 bias = *(const float4*)(vbias + oo);
        ushort4v st;
#pragma unroll
        for (int r = 0; r < 4; ++r) st[r] = f2b(acc[mi][ni][r] + ((const float*)&bias)[r]);
        *(ushort4v*)(Vb + dst) = st;
      }
    }
  }
}

// ---------------- V -> V^T  ([B,NH,S,HD] -> [B,NH,HD,S]) ----------------
__global__ __launch_bounds__(256) void transpose_v(
    const u16* __restrict__ Vb, u16* __restrict__ Vtb) {
  __shared__ u16 tile[64][72];
  const int st = blockIdx.x * 64, bh = blockIdx.y;
  const int t = threadIdx.x;
#pragma unroll
  for (int i = 0; i < 2; ++i) {
    int idx = i * 256 + t, row = idx >> 3, c8 = (idx & 7) * 8;
    *(short8*)(&tile[row][c8]) = *(const short8*)(Vb + ((size_t)bh * S_ + st + row) * HD_ + c8);
  }
  __syncthreads();
#pragma unroll
  for (int i = 0; i < 2; ++i) {
    int idx = i * 256 + t, d = idx >> 3, c8 = (idx & 7) * 8;
    short8 v;
#pragma unroll
    for (int j = 0; j < 8; ++j) v[j] = (short)tile[c8 + j][d];
    *(short8*)(Vtb + ((size_t)bh * HD_ + d) * S_ + st + c8) = v;
  }
}

// ---------------- flash attention: S^T = K·Q^T, fixed-shift softmax, O^T = V^T·P^T ----
// Round-3: rel/mask loads hoisted to iteration top (burst issue, latency overlap);
// K/Vt tiles register-double-buffered so global loads fly during compute.
__global__ __launch_bounds__(256, 3) void flash_attn(
    const u16* __restrict__ Qb, const u16* __restrict__ Kb,
    const u16* __restrict__ Vtb, const u16* __restrict__ relb,
    const unsigned char* __restrict__ mask, u16* __restrict__ ctxb) {
  const int qt_blk = blockIdx.x, h = blockIdx.y, b = blockIdx.z;
  const int bh = b * NH_ + h, q0 = qt_blk * 128;
  const int t = threadIdx.x, lane = t & 63, wv = t >> 6;
  const int ln = lane & 15, q8 = lane >> 4;

  __shared__ u16 Ks[128 * 72];      // [k][64+8]
  __shared__ u16 Vts[64 * 136];     // [d][128+8]
  __shared__ u16 Pbuf[4 * 32 * 40]; // per-wave [q 32][32+8]
  u16* Pw = Pbuf + wv * 1280;

  // staging decomposition (same for every tile)
  const int krow = t >> 3, kcol = (t & 7) * 8;    // K: 4 chunks of 32 rows
  const int vrow = t >> 4, vcol = (t & 15) * 8;   // Vt: 4 chunks of 16 rows

  short8 kreg[4], vreg[4];
#pragma unroll
  for (int i = 0; i < 4; ++i)
    kreg[i] = *(const short8*)(Kb + ((size_t)bh * S_ + i * 32 + krow) * HD_ + kcol);
#pragma unroll
  for (int i = 0; i < 4; ++i)
    vreg[i] = *(const short8*)(Vtb + ((size_t)bh * HD_ + i * 16 + vrow) * S_ + vcol);

  short8 qf[2][2];   // [qt][kc]
#pragma unroll
  for (int qt = 0; qt < 2; ++qt)
#pragma unroll
    for (int kc = 0; kc < 2; ++kc)
      qf[qt][kc] = *(const short8*)(Qb + ((size_t)bh * S_ + q0 + wv * 32 + qt * 16 + ln) * HD_ + kc * 32 + q8 * 8);

  f32x4 Oa[4][2] = {};   // [mt(d)][qt]
  float rs2[2] = {0.f, 0.f};

  for (int kt128 = 0; kt128 < 8; ++kt128) {
    const int k0 = kt128 * 128;

    // ---- burst-issue rel + mask loads for this whole iteration ----
    ushort4v relg[4][2][2];   // [kvc][sub][qt]
    uchar4v  mg[4][2];        // [kvc][sub]
#pragma unroll
    for (int kvc = 0; kvc < 4; ++kvc)
#pragma unroll
      for (int sub = 0; sub < 2; ++sub) {
        const int kt = kvc * 2 + sub, ktg = kt128 * 8 + kt;
        mg[kvc][sub] = *(const uchar4v*)(mask + b * S_ + k0 + kt * 16 + q8 * 4);
#pragma unroll
        for (int qt = 0; qt < 2; ++qt) {
          const int qtg = qt_blk * 8 + wv * 2 + qt;
          relg[kvc][sub][qt] = *(const ushort4v*)(relb +
              ((((size_t)h * 64 + ktg) * 64 + qtg) * 4 + q8) * 64 + ln * 4);
        }
      }

    __syncthreads();
    // ---- commit prefetched tile to LDS ----
#pragma unroll
    for (int i = 0; i < 4; ++i)
      *(short8*)(Ks + (i * 32 + krow) * 72 + kcol) = kreg[i];
#pragma unroll
    for (int i = 0; i < 4; ++i)
      *(short8*)(Vts + (i * 16 + vrow) * 136 + vcol) = vreg[i];
    // ---- issue next tile's global loads; they drain during compute ----
    if (kt128 < 7) {
      const int k0n = k0 + 128;
#pragma unroll
      for (int i = 0; i < 4; ++i)
        kreg[i] = *(const short8*)(Kb + ((size_t)bh * S_ + k0n + i * 32 + krow) * HD_ + kcol);
#pragma unroll
      for (int i = 0; i < 4; ++i)
        vreg[i] = *(const short8*)(Vtb + ((size_t)bh * HD_ + i * 16 + vrow) * S_ + k0n + vcol);
    }
    __syncthreads();

    // ---- compute ----
#pragma unroll
    for (int kvc = 0; kvc < 4; ++kvc) {
#pragma unroll
      for (int sub = 0; sub < 2; ++sub) {
        const int kt = kvc * 2 + sub;
        short8 kf0 = *(const short8*)(Ks + (kt * 16 + ln) * 72 + q8 * 8);
        short8 kf1 = *(const short8*)(Ks + (kt * 16 + ln) * 72 + 32 + q8 * 8);
        uchar4v m4 = mg[kvc][sub];
        f32x4 mbase;
#pragma unroll
        for (int r = 0; r < 4; ++r) mbase[r] = (m4[r] ? -1e30f : 0.f) - 8.0f;  // fixed shift
#pragma unroll
        for (int qt = 0; qt < 2; ++qt) {
          ushort4v r4 = relg[kvc][sub][qt];
          f32x4 sc;
#pragma unroll
          for (int r = 0; r < 4; ++r) sc[r] = b2f(r4[r]) + mbase[r];
          sc = __builtin_amdgcn_mfma_f32_16x16x32_bf16(kf0, qf[qt][0], sc, 0, 0, 0);
          sc = __builtin_amdgcn_mfma_f32_16x16x32_bf16(kf1, qf[qt][1], sc, 0, 0, 0);
          float p0 = __expf(sc[0]), p1 = __expf(sc[1]);
          float p2 = __expf(sc[2]), p3 = __expf(sc[3]);
          rs2[qt] += (p0 + p1) + (p2 + p3);
          uint2v pw;
          pw[0] = (unsigned)f2b(p0) | ((unsigned)f2b(p1) << 16);
          pw[1] = (unsigned)f2b(p2) | ((unsigned)f2b(p3) << 16);
          *(uint2v*)(Pw + (qt * 16 + ln) * 40 + sub * 16 + q8 * 4) = pw;
        }
      }
      short8 pf0 = *(const short8*)(Pw + ln * 40 + q8 * 8);
      short8 pf1 = *(const short8*)(Pw + (16 + ln) * 40 + q8 * 8);
#pragma unroll
      for (int mt = 0; mt < 4; ++mt) {
        short8 vf = *(const short8*)(Vts + (mt * 16 + ln) * 136 + kvc * 32 + q8 * 8);
        Oa[mt][0] = __builtin_amdgcn_mfma_f32_16x16x32_bf16(vf, pf0, Oa[mt][0], 0, 0, 0);
        Oa[mt][1] = __builtin_amdgcn_mfma_f32_16x16x32_bf16(vf, pf1, Oa[mt][1], 0, 0, 0);
      }
    }
  }

  float inv[2];
#pragma unroll
  for (int qt = 0; qt < 2; ++qt) {
    rs2[qt] += __shfl_xor(rs2[qt], 16, 64);
    rs2[qt] += __shfl_xor(rs2[qt], 32, 64);
    inv[qt] = 1.f / rs2[qt];
  }
#pragma unroll
  for (int mt = 0; mt < 4; ++mt)
#pragma unroll
    for (int qt = 0; qt < 2; ++qt) {
      const int q = q0 + wv * 32 + qt * 16 + ln;
      ushort4v st;
#pragma unroll
      for (int r = 0; r < 4; ++r) st[r] = f2b(Oa[mt][qt][r] * inv[qt]);
      *(ushort4v*)(ctxb + ((size_t)(b * S_ + q)) * HID_ + h * 64 + mt * 16 + q8 * 4) = st;
    }
}

// ---------------- output projection GEMM, D[o][s]; +bias +residual ----------------
__global__ __launch_bounds__(256) void gemm_out(
    const u16* __restrict__ W, const u16* __restrict__ X,
    const float* __restrict__ bout, const float* __restrict__ xres,
    u16* __restrict__ hb) {
  constexpr int K = HID_;
  __shared__ u16 Ws[128 * 32];
  __shared__ u16 Xs[128 * 32];
  const int o0 = blockIdx.x * 128, s0 = blockIdx.y * 128;
  const int t = threadIdx.x, lane = t & 63, wv = t >> 6;
  const int wr = wv >> 1, wc = wv & 1, ln = lane & 15, q8 = lane >> 4;
  f32x4 acc[4][4] = {};

  for (int kt = 0; kt < K / 32; ++kt) {
    const int k0 = kt * 32;
#pragma unroll
    for (int c = 0; c < 2; ++c) {
      int idx = c * 256 + t, row = idx >> 2, cc = (idx & 3) * 8;
      llds16(W + (size_t)(o0 + row) * K + k0 + cc, Ws + (size_t)(c * 256 + wv * 64) * 8);
      llds16(X + (size_t)(s0 + row) * K + k0 + cc, Xs + (size_t)(c * 256 + wv * 64) * 8);
    }
    __syncthreads();
    short8 of[4], sf[4];
#pragma unroll
    for (int mi = 0; mi < 4; ++mi)
      of[mi] = *(const short8*)(Ws + (wr * 64 + mi * 16 + ln) * 32 + q8 * 8);
#pragma unroll
    for (int ni = 0; ni < 4; ++ni)
      sf[ni] = *(const short8*)(Xs + (wc * 64 + ni * 16 + ln) * 32 + q8 * 8);
#pragma unroll
    for (int mi = 0; mi < 4; ++mi)
#pragma unroll
      for (int ni = 0; ni < 4; ++ni)
        acc[mi][ni] = __builtin_amdgcn_mfma_f32_16x16x32_bf16(of[mi], sf[ni], acc[mi][ni], 0, 0, 0);
    __syncthreads();
  }

#pragma unroll
  for (int mi = 0; mi < 4; ++mi) {
    const int ob = o0 + wr * 64 + mi * 16 + q8 * 4;
    float4 b4 = *(const float4*)(bout + ob);
#pragma unroll
    for (int ni = 0; ni < 4; ++ni) {
      const int s = s0 + wc * 64 + ni * 16 + ln;
      float4 x4 = *(const float4*)(xres + (size_t)s * HID_ + ob);
      ushort4v st;
#pragma unroll
      for (int r = 0; r < 4; ++r)
        st[r] = f2b(acc[mi][ni][r] + ((const float*)&b4)[r] + ((const float*)&x4)[r]);
      *(ushort4v*)(hb + (size_t)s * HID_ + ob) = st;
    }
  }
}

// ---------------- LayerNorm, one wave per row ----------------
__global__ __launch_bounds__(256) void ln_kernel(
    const u16* __restrict__ hb, const float* __restrict__ gamma,
    const float* __restrict__ beta, float* __restrict__ out) {
  const int lane = threadIdx.x & 63, wv = threadIdx.x >> 6;
  const int row = blockIdx.x * 4 + wv;
  const u16* hr = hb + (size_t)row * HID_;
  float v[16];
  short8 a = *(const short8*)(hr + lane * 16);
  short8 c = *(const short8*)(hr + lane * 16 + 8);
#pragma unroll
  for (int j = 0; j < 8; ++j) { v[j] = b2f((u16)a[j]); v[8 + j] = b2f((u16)c[j]); }
  float sum = 0.f, sq = 0.f;
#pragma unroll
  for (int j = 0; j < 16; ++j) { sum += v[j]; sq += v[j] * v[j]; }
#pragma unroll
  for (int off = 1; off < 64; off <<= 1) {
    sum += __shfl_xor(sum, off, 64);
    sq  += __shfl_xor(sq, off, 64);
  }
  const float mu = sum * (1.f / HID_);
  const float var = sq * (1.f / HID_) - mu * mu;
  const float inv = 1.f / sqrtf(var + 1e-12f);
#pragma unroll
  for (int j = 0; j < 16; ++j) {
    const int n = lane * 16 + j;
    out[(size_t)row * HID_ + n] = (v[j] - mu) * inv * gamma[n] + beta[n];
  }
}

extern "C" void kernel_launch(void* const* d_in, const int* in_sizes, int n_in,
                              void* d_out, int out_size, void* d_ws, size_t ws_size,
                              hipStream_t stream) {
  (void)in_sizes; (void)n_in; (void)out_size; (void)ws_size;
  const float* x     = (const float*)d_in[0];
  const unsigned char* mask = (const unsigned char*)d_in[1];
  const float* relp  = (const float*)d_in[2];
  const float* rel2  = (const float*)d_in[3];
  const float* wqkv  = (const float*)d_in[4];
  const float* qbias = (const float*)d_in[5];
  const float* vbias = (const float*)d_in[6];
  const float* wout  = (const float*)d_in[7];
  const float* bout  = (const float*)d_in[8];
  const float* gamma = (const float*)d_in[9];
  const float* beta  = (const float*)d_in[10];
  float* out = (float*)d_out;

  char* ws = (char*)d_ws;
  const size_t MB = (size_t)1 << 20;
  u16* xb    = (u16*)(ws + 0 * MB);    // 16 MB (reused as Vtb after gemm_qkv)
  u16* wqkvb = (u16*)(ws + 16 * MB);   // 6 MB
  u16* woutb = (u16*)(ws + 22 * MB);   // 2 MB
  u16* relb  = (u16*)(ws + 24 * MB);   // 32 MB (permuted)
  u16* Qb    = (u16*)(ws + 56 * MB);   // 16 MB
  u16* Kb    = (u16*)(ws + 72 * MB);   // 16 MB
  u16* Vb    = (u16*)(ws + 88 * MB);   // 16 MB  [B,NH,S,HD]
  u16* ctxb  = (u16*)(ws + 104 * MB);  // 16 MB
  u16* hb    = (u16*)(ws + 120 * MB);  // 16 MB
  u16* Vtb   = xb;                     // xb dead after gemm_qkv (stream-ordered)

  prep_cvt<<<1024, 256, 0, stream>>>(x, wqkv, wout, xb, wqkvb, woutb);
  rel_perm<<<dim3(64, 16), 256, 0, stream>>>(relp, rel2, relb);
  gemm_qkv<<<dim3(24, 64), 256, 0, stream>>>(wqkvb, xb, qbias, vbias, Qb, Kb, Vb);
  transpose_v<<<dim3(16, 128), 256, 0, stream>>>(Vb, Vtb);
  flash_attn<<<dim3(8, 16, 8), 256, 0, stream>>>(Qb, Kb, Vtb, relb, mask, ctxb);
  gemm_out<<<dim3(8, 64), 256, 0, stream>>>(woutb, ctxb, bout, x, hb);
  ln_kernel<<<2048, 256, 0, stream>>>(hb, gamma, beta, out);
}

// Round 4
// 443.720 us; speedup vs baseline: 1.2066x; 1.0671x over previous
//
#include <hip/hip_runtime.h>
#include <stdint.h>
#include <stddef.h>

typedef unsigned short u16;
typedef __attribute__((ext_vector_type(8))) short short8;
typedef __attribute__((ext_vector_type(4))) float f32x4;
typedef __attribute__((ext_vector_type(4))) unsigned short ushort4v;
typedef __attribute__((ext_vector_type(4))) unsigned char uchar4v;
typedef __attribute__((ext_vector_type(2))) unsigned int uint2v;

constexpr int B_ = 8, S_ = 1024, HID_ = 1024, NH_ = 16, HD_ = 64;

__device__ __forceinline__ u16 f2b(float f) {
  unsigned int u = __builtin_bit_cast(unsigned int, f);
  u += 0x7fff + ((u >> 16) & 1);   // RNE
  return (u16)(u >> 16);
}
__device__ __forceinline__ float b2f(u16 s) {
  unsigned int u = ((unsigned int)s) << 16;
  return __builtin_bit_cast(float, u);
}
__device__ __forceinline__ void llds16(const void* g, void* l) {
  __builtin_amdgcn_global_load_lds((__attribute__((address_space(1))) void*)g,
                                   (__attribute__((address_space(3))) void*)l, 16, 0, 0);
}

// ---------------- fp32 -> bf16 conversions ----------------
__global__ __launch_bounds__(256) void prep_cvt(
    const float* __restrict__ x, const float* __restrict__ wqkv,
    const float* __restrict__ wout, u16* __restrict__ xb,
    u16* __restrict__ wqkvb, u16* __restrict__ woutb) {
  const int NX4 = B_ * S_ * HID_ / 4, NW14 = 3 * HID_ * HID_ / 4, NW24 = HID_ * HID_ / 4;
  const int tot = NX4 + NW14 + NW24;
  for (int i = blockIdx.x * blockDim.x + threadIdx.x; i < tot; i += gridDim.x * blockDim.x) {
    const float4* s; u16* d; int j;
    if (i < NX4)              { s = (const float4*)x;    d = xb;    j = i; }
    else if (i < NX4 + NW14)  { s = (const float4*)wqkv; d = wqkvb; j = i - NX4; }
    else                      { s = (const float4*)wout; d = woutb; j = i - NX4 - NW14; }
    float4 v = s[j];
    ushort4v o; o[0] = f2b(v.x); o[1] = f2b(v.y); o[2] = f2b(v.z); o[3] = f2b(v.w);
    *(ushort4v*)(d + 4 * (size_t)j) = o;
  }
}

// ---------------- rel_pos + rel_2d_pos -> bf16, permuted to S^T C-fragment order ----
// elem (h,q,k): ktg=k>>4, qtg=q>>4, qk=(k&15)>>2, rk=k&3, lq=q&15
// flat = (((h*64+ktg)*64+qtg)*4+qk)*64 + lq*4 + rk
__global__ __launch_bounds__(256) void rel_perm(
    const float* __restrict__ a, const float* __restrict__ b, u16* __restrict__ relb) {
  __shared__ u16 lbuf[16 * 1032];
  const int qtg = blockIdx.x, h = blockIdx.y;
  const int t = threadIdx.x;
#pragma unroll
  for (int it = 0; it < 16; ++it) {
    int idx = it * 256 + t;
    int lq = idx >> 8, kc = idx & 255;
    size_t src = ((size_t)h * S_ + qtg * 16 + lq) * S_ + kc * 4;
    float4 va = *(const float4*)(a + src);
    float4 vb = *(const float4*)(b + src);
    ushort4v o;
    o[0] = f2b(va.x + vb.x); o[1] = f2b(va.y + vb.y);
    o[2] = f2b(va.z + vb.z); o[3] = f2b(va.w + vb.w);
    *(ushort4v*)(lbuf + lq * 1032 + kc * 4) = o;
  }
  __syncthreads();
#pragma unroll
  for (int it = 0; it < 16; ++it) {
    int c = it * 16 + (t >> 4);
    int ktg = c >> 2, qk = c & 3, lq = t & 15;
    ushort4v v = *(const ushort4v*)(lbuf + lq * 1032 + ktg * 16 + qk * 4);
    *(ushort4v*)(relb + ((((size_t)h * 64 + ktg) * 64 + qtg) * 4 + qk) * 64 + lq * 4) = v;
  }
}

// ---------------- QKV projection GEMM, D[o][s]; LDS-transposed coalesced epilogue ----
__global__ __launch_bounds__(256) void gemm_qkv(
    const u16* __restrict__ W, const u16* __restrict__ X,
    const float* __restrict__ qbias, const float* __restrict__ vbias,
    u16* __restrict__ Qb, u16* __restrict__ Kb, u16* __restrict__ Vb) {
  constexpr int K = HID_;
  __shared__ u16 smem[128 * 136];           // staging (2x4096) overlaid with epilogue buf
  u16* Ws = smem;
  u16* Xs = smem + 4096;
  const int o0 = blockIdx.x * 128, s0 = blockIdx.y * 128;
  const int t = threadIdx.x, lane = t & 63, wv = t >> 6;
  const int wr = wv >> 1, wc = wv & 1, ln = lane & 15, q8 = lane >> 4;
  f32x4 acc[4][4] = {};

  for (int kt = 0; kt < K / 32; ++kt) {
    const int k0 = kt * 32;
#pragma unroll
    for (int c = 0; c < 2; ++c) {
      int idx = c * 256 + t, row = idx >> 2, cc = (idx & 3) * 8;
      llds16(W + (size_t)(o0 + row) * K + k0 + cc, Ws + (size_t)(c * 256 + wv * 64) * 8);
      llds16(X + (size_t)(s0 + row) * K + k0 + cc, Xs + (size_t)(c * 256 + wv * 64) * 8);
    }
    __syncthreads();
    short8 of[4], sf[4];
#pragma unroll
    for (int mi = 0; mi < 4; ++mi)
      of[mi] = *(const short8*)(Ws + (wr * 64 + mi * 16 + ln) * 32 + q8 * 8);
#pragma unroll
    for (int ni = 0; ni < 4; ++ni)
      sf[ni] = *(const short8*)(Xs + (wc * 64 + ni * 16 + ln) * 32 + q8 * 8);
#pragma unroll
    for (int mi = 0; mi < 4; ++mi)
#pragma unroll
      for (int ni = 0; ni < 4; ++ni)
        acc[mi][ni] = __builtin_amdgcn_mfma_f32_16x16x32_bf16(of[mi], sf[ni], acc[mi][ni], 0, 0, 0);
    __syncthreads();
  }

  const int sec = o0 >> 10;   // 0=Q 1=K 2=V (block-uniform)
  // phase 1: bias/scale applied, bf16 into buf[s 128][o 128, pitch 136]
#pragma unroll
  for (int mi = 0; mi < 4; ++mi) {
    const int ocol = wr * 64 + mi * 16 + q8 * 4;
    const int oo = (o0 + ocol) & 1023;
    float4 b4;
    if (sec == 0)      b4 = *(const float4*)(qbias + oo);
    else if (sec == 2) b4 = *(const float4*)(vbias + oo);
    else               b4 = float4{0.f, 0.f, 0.f, 0.f};
#pragma unroll
    for (int ni = 0; ni < 4; ++ni) {
      const int srow = wc * 64 + ni * 16 + ln;
      u16 e[4];
#pragma unroll
      for (int r = 0; r < 4; ++r) {
        float v = acc[mi][ni][r] + ((const float*)&b4)[r];
        if (sec == 0) v *= 0.125f;
        e[r] = f2b(v);
      }
      uint2v pw;
      pw[0] = (unsigned)e[0] | ((unsigned)e[1] << 16);
      pw[1] = (unsigned)e[2] | ((unsigned)e[3] << 16);
      *(uint2v*)(smem + srow * 136 + ocol) = pw;
    }
  }
  __syncthreads();
  // phase 2: fully-coalesced 16B stores, 8 lanes per 128B (s,h) segment
  u16* dst = (sec == 0) ? Qb : (sec == 1) ? Kb : Vb;
#pragma unroll
  for (int i = 0; i < 8; ++i) {
    int flat = i * 256 + t;
    int srow = flat >> 4, c8 = (flat & 15) * 8;
    short8 v = *(const short8*)(smem + srow * 136 + c8);
    int oo = (o0 + c8) & 1023, hh = oo >> 6, dd = oo & 63;
    int s = s0 + srow, bb = s >> 10, ss = s & 1023;
    *(short8*)(dst + ((size_t)(bb * NH_ + hh) * S_ + ss) * HD_ + dd) = v;
  }
}

// ---------------- V -> V^T  ([B,NH,S,HD] -> [B,NH,HD,S]) ----------------
__global__ __launch_bounds__(256) void transpose_v(
    const u16* __restrict__ Vb, u16* __restrict__ Vtb) {
  __shared__ u16 tile[64][72];
  const int st = blockIdx.x * 64, bh = blockIdx.y;
  const int t = threadIdx.x;
#pragma unroll
  for (int i = 0; i < 2; ++i) {
    int idx = i * 256 + t, row = idx >> 3, c8 = (idx & 7) * 8;
    *(short8*)(&tile[row][c8]) = *(const short8*)(Vb + ((size_t)bh * S_ + st + row) * HD_ + c8);
  }
  __syncthreads();
#pragma unroll
  for (int i = 0; i < 2; ++i) {
    int idx = i * 256 + t, d = idx >> 3, c8 = (idx & 7) * 8;
    short8 v;
#pragma unroll
    for (int j = 0; j < 8; ++j) v[j] = (short)tile[c8 + j][d];
    *(short8*)(Vtb + ((size_t)bh * HD_ + d) * S_ + st + c8) = v;
  }
}

// ---------------- flash attention: S^T = K·Q^T, fixed-shift softmax, O^T = V^T·P^T ----
__global__ __launch_bounds__(256, 3) void flash_attn(
    const u16* __restrict__ Qb, const u16* __restrict__ Kb,
    const u16* __restrict__ Vtb, const u16* __restrict__ relb,
    const unsigned char* __restrict__ mask, u16* __restrict__ ctxb) {
  const int qt_blk = blockIdx.x, h = blockIdx.y, b = blockIdx.z;
  const int bh = b * NH_ + h, q0 = qt_blk * 128;
  const int t = threadIdx.x, lane = t & 63, wv = t >> 6;
  const int ln = lane & 15, q8 = lane >> 4;

  __shared__ u16 Ks[128 * 72];      // [k][64+8]; reused as O epilogue buffer
  __shared__ u16 Vts[64 * 136];     // [d][128+8]
  __shared__ u16 Pbuf[4 * 32 * 40]; // per-wave [q 32][32+8]
  u16* Pw = Pbuf + wv * 1280;

  const int krow = t >> 3, kcol = (t & 7) * 8;
  const int vrow = t >> 4, vcol = (t & 15) * 8;

  short8 kreg[4], vreg[4];
#pragma unroll
  for (int i = 0; i < 4; ++i)
    kreg[i] = *(const short8*)(Kb + ((size_t)bh * S_ + i * 32 + krow) * HD_ + kcol);
#pragma unroll
  for (int i = 0; i < 4; ++i)
    vreg[i] = *(const short8*)(Vtb + ((size_t)bh * HD_ + i * 16 + vrow) * S_ + vcol);

  short8 qf[2][2];
#pragma unroll
  for (int qt = 0; qt < 2; ++qt)
#pragma unroll
    for (int kc = 0; kc < 2; ++kc)
      qf[qt][kc] = *(const short8*)(Qb + ((size_t)bh * S_ + q0 + wv * 32 + qt * 16 + ln) * HD_ + kc * 32 + q8 * 8);

  f32x4 Oa[4][2] = {};   // [mt(d)][qt]
  float rs2[2] = {0.f, 0.f};

  for (int kt128 = 0; kt128 < 8; ++kt128) {
    const int k0 = kt128 * 128;

    // burst-issue rel + mask loads for this iteration (latency overlap)
    ushort4v relg[4][2][2];
    uchar4v  mg[4][2];
#pragma unroll
    for (int kvc = 0; kvc < 4; ++kvc)
#pragma unroll
      for (int sub = 0; sub < 2; ++sub) {
        const int kt = kvc * 2 + sub, ktg = kt128 * 8 + kt;
        mg[kvc][sub] = *(const uchar4v*)(mask + b * S_ + k0 + kt * 16 + q8 * 4);
#pragma unroll
        for (int qt = 0; qt < 2; ++qt) {
          const int qtg = qt_blk * 8 + wv * 2 + qt;
          relg[kvc][sub][qt] = *(const ushort4v*)(relb +
              ((((size_t)h * 64 + ktg) * 64 + qtg) * 4 + q8) * 64 + ln * 4);
        }
      }

    __syncthreads();
#pragma unroll
    for (int i = 0; i < 4; ++i)
      *(short8*)(Ks + (i * 32 + krow) * 72 + kcol) = kreg[i];
#pragma unroll
    for (int i = 0; i < 4; ++i)
      *(short8*)(Vts + (i * 16 + vrow) * 136 + vcol) = vreg[i];
    if (kt128 < 7) {
      const int k0n = k0 + 128;
#pragma unroll
      for (int i = 0; i < 4; ++i)
        kreg[i] = *(const short8*)(Kb + ((size_t)bh * S_ + k0n + i * 32 + krow) * HD_ + kcol);
#pragma unroll
      for (int i = 0; i < 4; ++i)
        vreg[i] = *(const short8*)(Vtb + ((size_t)bh * HD_ + i * 16 + vrow) * S_ + k0n + vcol);
    }
    __syncthreads();

#pragma unroll
    for (int kvc = 0; kvc < 4; ++kvc) {
#pragma unroll
      for (int sub = 0; sub < 2; ++sub) {
        const int kt = kvc * 2 + sub;
        short8 kf0 = *(const short8*)(Ks + (kt * 16 + ln) * 72 + q8 * 8);
        short8 kf1 = *(const short8*)(Ks + (kt * 16 + ln) * 72 + 32 + q8 * 8);
        uchar4v m4 = mg[kvc][sub];
        f32x4 mbase;
#pragma unroll
        for (int r = 0; r < 4; ++r) mbase[r] = (m4[r] ? -1e30f : 0.f) - 8.0f;
#pragma unroll
        for (int qt = 0; qt < 2; ++qt) {
          ushort4v r4 = relg[kvc][sub][qt];
          f32x4 sc;
#pragma unroll
          for (int r = 0; r < 4; ++r) sc[r] = b2f(r4[r]) + mbase[r];
          sc = __builtin_amdgcn_mfma_f32_16x16x32_bf16(kf0, qf[qt][0], sc, 0, 0, 0);
          sc = __builtin_amdgcn_mfma_f32_16x16x32_bf16(kf1, qf[qt][1], sc, 0, 0, 0);
          float p0 = __expf(sc[0]), p1 = __expf(sc[1]);
          float p2 = __expf(sc[2]), p3 = __expf(sc[3]);
          rs2[qt] += (p0 + p1) + (p2 + p3);
          uint2v pw;
          pw[0] = (unsigned)f2b(p0) | ((unsigned)f2b(p1) << 16);
          pw[1] = (unsigned)f2b(p2) | ((unsigned)f2b(p3) << 16);
          *(uint2v*)(Pw + (qt * 16 + ln) * 40 + sub * 16 + q8 * 4) = pw;
        }
      }
      short8 pf0 = *(const short8*)(Pw + ln * 40 + q8 * 8);
      short8 pf1 = *(const short8*)(Pw + (16 + ln) * 40 + q8 * 8);
#pragma unroll
      for (int mt = 0; mt < 4; ++mt) {
        short8 vf = *(const short8*)(Vts + (mt * 16 + ln) * 136 + kvc * 32 + q8 * 8);
        Oa[mt][0] = __builtin_amdgcn_mfma_f32_16x16x32_bf16(vf, pf0, Oa[mt][0], 0, 0, 0);
        Oa[mt][1] = __builtin_amdgcn_mfma_f32_16x16x32_bf16(vf, pf1, Oa[mt][1], 0, 0, 0);
      }
    }
  }

  float inv[2];
#pragma unroll
  for (int qt = 0; qt < 2; ++qt) {
    rs2[qt] += __shfl_xor(rs2[qt], 16, 64);
    rs2[qt] += __shfl_xor(rs2[qt], 32, 64);
    inv[qt] = 1.f / rs2[qt];
  }

  // epilogue: O^T -> [q][d] via wave-private LDS (reuse Ks), fully-coalesced stores
  __syncthreads();                       // all waves done reading Ks/Vts
  u16* Ob = Ks + wv * 2304;              // 32 rows x pitch 72
#pragma unroll
  for (int qt = 0; qt < 2; ++qt)
#pragma unroll
    for (int mt = 0; mt < 4; ++mt) {
      u16 e[4];
#pragma unroll
      for (int r = 0; r < 4; ++r) e[r] = f2b(Oa[mt][qt][r] * inv[qt]);
      uint2v pw;
      pw[0] = (unsigned)e[0] | ((unsigned)e[1] << 16);
      pw[1] = (unsigned)e[2] | ((unsigned)e[3] << 16);
      *(uint2v*)(Ob + (qt * 16 + ln) * 72 + mt * 16 + q8 * 4) = pw;
    }
  // no barrier: wave-private round-trip
#pragma unroll
  for (int p = 0; p < 4; ++p) {
    int row = p * 8 + (lane >> 3);
    int c8 = (lane & 7) * 8;
    short8 v = *(const short8*)(Ob + row * 72 + c8);
    int q = q0 + wv * 32 + row;
    *(short8*)(ctxb + ((size_t)(b * S_ + q)) * HID_ + h * 64 + c8) = v;
  }
}

// ---------------- output projection GEMM, D[o][s]; +bias +residual, coalesced ----
__global__ __launch_bounds__(256) void gemm_out(
    const u16* __restrict__ W, const u16* __restrict__ X,
    const float* __restrict__ bout, const float* __restrict__ xres,
    u16* __restrict__ hb) {
  constexpr int K = HID_;
  __shared__ u16 smem[128 * 136];
  u16* Ws = smem;
  u16* Xs = smem + 4096;
  const int o0 = blockIdx.x * 128, s0 = blockIdx.y * 128;
  const int t = threadIdx.x, lane = t & 63, wv = t >> 6;
  const int wr = wv >> 1, wc = wv & 1, ln = lane & 15, q8 = lane >> 4;
  f32x4 acc[4][4] = {};

  for (int kt = 0; kt < K / 32; ++kt) {
    const int k0 = kt * 32;
#pragma unroll
    for (int c = 0; c < 2; ++c) {
      int idx = c * 256 + t, row = idx >> 2, cc = (idx & 3) * 8;
      llds16(W + (size_t)(o0 + row) * K + k0 + cc, Ws + (size_t)(c * 256 + wv * 64) * 8);
      llds16(X + (size_t)(s0 + row) * K + k0 + cc, Xs + (size_t)(c * 256 + wv * 64) * 8);
    }
    __syncthreads();
    short8 of[4], sf[4];
#pragma unroll
    for (int mi = 0; mi < 4; ++mi)
      of[mi] = *(const short8*)(Ws + (wr * 64 + mi * 16 + ln) * 32 + q8 * 8);
#pragma unroll
    for (int ni = 0; ni < 4; ++ni)
      sf[ni] = *(const short8*)(Xs + (wc * 64 + ni * 16 + ln) * 32 + q8 * 8);
#pragma unroll
    for (int mi = 0; mi < 4; ++mi)
#pragma unroll
      for (int ni = 0; ni < 4; ++ni)
        acc[mi][ni] = __builtin_amdgcn_mfma_f32_16x16x32_bf16(of[mi], sf[ni], acc[mi][ni], 0, 0, 0);
    __syncthreads();
  }

  // phase 1: acc + bias -> bf16 into buf[s][o]
#pragma unroll
  for (int mi = 0; mi < 4; ++mi) {
    const int ocol = wr * 64 + mi * 16 + q8 * 4;
    float4 b4 = *(const float4*)(bout + o0 + ocol);
#pragma unroll
    for (int ni = 0; ni < 4; ++ni) {
      const int srow = wc * 64 + ni * 16 + ln;
      u16 e[4];
#pragma unroll
      for (int r = 0; r < 4; ++r) e[r] = f2b(acc[mi][ni][r] + ((const float*)&b4)[r]);
      uint2v pw;
      pw[0] = (unsigned)e[0] | ((unsigned)e[1] << 16);
      pw[1] = (unsigned)e[2] | ((unsigned)e[3] << 16);
      *(uint2v*)(smem + srow * 136 + ocol) = pw;
    }
  }
  __syncthreads();
  // phase 2: +residual (coalesced fp32 reads), coalesced 16B stores
#pragma unroll
  for (int i = 0; i < 8; ++i) {
    int flat = i * 256 + t;
    int srow = flat >> 4, c8 = (flat & 15) * 8;
    short8 v = *(const short8*)(smem + srow * 136 + c8);
    int s = s0 + srow, o = o0 + c8;
    float4 x0 = *(const float4*)(xres + (size_t)s * HID_ + o);
    float4 x1 = *(const float4*)(xres + (size_t)s * HID_ + o + 4);
    short8 st;
#pragma unroll
    for (int j = 0; j < 4; ++j) st[j] = (short)f2b(b2f((u16)v[j]) + ((const float*)&x0)[j]);
#pragma unroll
    for (int j = 0; j < 4; ++j) st[4 + j] = (short)f2b(b2f((u16)v[4 + j]) + ((const float*)&x1)[j]);
    *(short8*)(hb + (size_t)s * HID_ + o) = st;
  }
}

// ---------------- LayerNorm, one wave per row ----------------
__global__ __launch_bounds__(256) void ln_kernel(
    const u16* __restrict__ hb, const float* __restrict__ gamma,
    const float* __restrict__ beta, float* __restrict__ out) {
  const int lane = threadIdx.x & 63, wv = threadIdx.x >> 6;
  const int row = blockIdx.x * 4 + wv;
  const u16* hr = hb + (size_t)row * HID_;
  float v[16];
  short8 a = *(const short8*)(hr + lane * 16);
  short8 c = *(const short8*)(hr + lane * 16 + 8);
#pragma unroll
  for (int j = 0; j < 8; ++j) { v[j] = b2f((u16)a[j]); v[8 + j] = b2f((u16)c[j]); }
  float sum = 0.f, sq = 0.f;
#pragma unroll
  for (int j = 0; j < 16; ++j) { sum += v[j]; sq += v[j] * v[j]; }
#pragma unroll
  for (int off = 1; off < 64; off <<= 1) {
    sum += __shfl_xor(sum, off, 64);
    sq  += __shfl_xor(sq, off, 64);
  }
  const float mu = sum * (1.f / HID_);
  const float var = sq * (1.f / HID_) - mu * mu;
  const float inv = 1.f / sqrtf(var + 1e-12f);
#pragma unroll
  for (int j = 0; j < 16; ++j) {
    const int n = lane * 16 + j;
    out[(size_t)row * HID_ + n] = (v[j] - mu) * inv * gamma[n] + beta[n];
  }
}

extern "C" void kernel_launch(void* const* d_in, const int* in_sizes, int n_in,
                              void* d_out, int out_size, void* d_ws, size_t ws_size,
                              hipStream_t stream) {
  (void)in_sizes; (void)n_in; (void)out_size; (void)ws_size;
  const float* x     = (const float*)d_in[0];
  const unsigned char* mask = (const unsigned char*)d_in[1];
  const float* relp  = (const float*)d_in[2];
  const float* rel2  = (const float*)d_in[3];
  const float* wqkv  = (const float*)d_in[4];
  const float* qbias = (const float*)d_in[5];
  const float* vbias = (const float*)d_in[6];
  const float* wout  = (const float*)d_in[7];
  const float* bout  = (const float*)d_in[8];
  const float* gamma = (const float*)d_in[9];
  const float* beta  = (const float*)d_in[10];
  float* out = (float*)d_out;

  char* ws = (char*)d_ws;
  const size_t MB = (size_t)1 << 20;
  u16* xb    = (u16*)(ws + 0 * MB);    // 16 MB (reused as Vtb after gemm_qkv)
  u16* wqkvb = (u16*)(ws + 16 * MB);   // 6 MB
  u16* woutb = (u16*)(ws + 22 * MB);   // 2 MB
  u16* relb  = (u16*)(ws + 24 * MB);   // 32 MB (permuted)
  u16* Qb    = (u16*)(ws + 56 * MB);   // 16 MB
  u16* Kb    = (u16*)(ws + 72 * MB);   // 16 MB
  u16* Vb    = (u16*)(ws + 88 * MB);   // 16 MB  [B,NH,S,HD]
  u16* ctxb  = (u16*)(ws + 104 * MB);  // 16 MB
  u16* hb    = (u16*)(ws + 120 * MB);  // 16 MB
  u16* Vtb   = xb;                     // xb dead after gemm_qkv (stream-ordered)

  prep_cvt<<<1024, 256, 0, stream>>>(x, wqkv, wout, xb, wqkvb, woutb);
  rel_perm<<<dim3(64, 16), 256, 0, stream>>>(relp, rel2, relb);
  gemm_qkv<<<dim3(24, 64), 256, 0, stream>>>(wqkvb, xb, qbias, vbias, Qb, Kb, Vb);
  transpose_v<<<dim3(16, 128), 256, 0, stream>>>(Vb, Vtb);
  flash_attn<<<dim3(8, 16, 8), 256, 0, stream>>>(Qb, Kb, Vtb, relb, mask, ctxb);
  gemm_out<<<dim3(8, 64), 256, 0, stream>>>(woutb, ctxb, bout, x, hb);
  ln_kernel<<<2048, 256, 0, stream>>>(hb, gamma, beta, out);
}